// Round 3
// baseline (333.105 us; speedup 1.0000x reference)
//
#include <hip/hip_runtime.h>
#include <hip/hip_cooperative_groups.h>
#include <math.h>

namespace cg = cooperative_groups;

// Problem constants
#define B 64
#define NI 1024
#define NO 1024
#define NC 10
#define GRID 512
#define OG 16     // o's per wave in partial phases
#define NSPLIT 8  // i-split across blocks (after in-block 4-wave reduce)

typedef float f4 __attribute__((ext_vector_type(4)));

__device__ __forceinline__ float lt_of(float x) {
    // log(tanh(100*|x|)), clamped so 0-mask * (-1e30) == 0 stays clean (no inf*0)
    return fmaxf(logf(tanhf(100.0f * fabsf(x))), -1e30f);
}

// Partial phase for one layer. lanes = b; weights via wave-uniform scalar loads.
//   ph[s][o][b] = sum_{i in seg} xT[i][b] * fc[o][i] * (v[o][i] > 0)
//   ps[s][o][b] = sum_{i in seg} ltT[i][b] * (v[o][i] > 0)
// Block: 64 o-group x 8 i-split; 4 waves take 32-i subranges; LDS-reduce to one partial.
__device__ __forceinline__ void layer_partial(
    const float* __restrict__ xT, const float* __restrict__ ltT,
    const float* __restrict__ fcw, const float* __restrict__ vw,
    float* __restrict__ ph, float* __restrict__ ps, float* smem)
{
    const int blk = blockIdx.x;
    const int og  = blk & 63;          // o-group
    const int isb = blk >> 6;          // i-split 0..7
    const int w    = threadIdx.x >> 6;
    const int lane = threadIdx.x & 63;
    const int o0  = og * OG;
    // force wave-uniformity so weight addresses become scalar (s_load) addresses
    const int i0u = __builtin_amdgcn_readfirstlane(isb * 128 + w * 32);

    float ah[OG], as_[OG];
    #pragma unroll
    for (int o = 0; o < OG; ++o) { ah[o] = 0.f; as_[o] = 0.f; }

    float xv[8], lv[8], xn[8], ln[8];
    #pragma unroll
    for (int j = 0; j < 8; ++j) {
        xv[j] = xT [(i0u + j) * B + lane];
        lv[j] = ltT[(i0u + j) * B + lane];
    }
    for (int ic = 0; ic < 32; ic += 8) {
        if (ic < 24) {          // prefetch next 8-i chunk of activations
            #pragma unroll
            for (int j = 0; j < 8; ++j) {
                xn[j] = xT [(i0u + ic + 8 + j) * B + lane];
                ln[j] = ltT[(i0u + ic + 8 + j) * B + lane];
            }
        }
        #pragma unroll
        for (int o = 0; o < OG; ++o) {
            const float* fp = &fcw[(o0 + o) * NI + i0u + ic];  // uniform -> s_load
            const float* vp = &vw [(o0 + o) * NI + i0u + ic];
            #pragma unroll
            for (int j = 0; j < 8; ++j) {
                float fv = fp[j], vv = vp[j];
                float wf = vv > 0.f ? fv : 0.f;   // scalar cselect
                float wm = vv > 0.f ? 1.f : 0.f;
                ah[o]  = fmaf(wf, xv[j], ah[o]);
                as_[o] = fmaf(wm, lv[j], as_[o]);
            }
        }
        if (ic < 24) {
            #pragma unroll
            for (int j = 0; j < 8; ++j) { xv[j] = xn[j]; lv[j] = ln[j]; }
        }
    }
    // in-block reduce over the 4 waves' i-subranges
    #pragma unroll
    for (int o = 0; o < OG; ++o) {
        smem[w * 2048 +        o * B + lane] = ah[o];
        smem[w * 2048 + 1024 + o * B + lane] = as_[o];
    }
    __syncthreads();
    const int tid = threadIdx.x;
    #pragma unroll
    for (int k = 0; k < 8; ++k) {
        int f = tid + k * 256;                     // 0..2047
        float s = smem[f] + smem[2048 + f] + smem[4096 + f] + smem[6144 + f];
        float* dst = (f >> 10) ? ps : ph;
        dst[isb * (NO * B) + o0 * B + (f & 1023)] = s;   // [s][o][b], coalesced
    }
}

__global__ __launch_bounds__(256, 2) void harsanyi_fused(
    const float* __restrict__ x,
    const float* __restrict__ v0, const float* __restrict__ fc0, const float* __restrict__ hd0,
    const float* __restrict__ v1, const float* __restrict__ fc1, const float* __restrict__ hd1,
    float* __restrict__ y,
    float* __restrict__ ph, float* __restrict__ ps,
    float* __restrict__ xT, float* __restrict__ ltT,
    float* __restrict__ h0T, float* __restrict__ lt1T, float* __restrict__ h1T)
{
    cg::grid_group grid = cg::this_grid();
    __shared__ float smem[8192];
    const int blk = blockIdx.x, tid = threadIdx.x;

    // ---- P0: transpose x -> xT[i][b] and ltT[i][b] via LDS 32x32 tiles ----
    if (blk < 64) {
        const int b0 = (blk & 1) * 32, i0 = (blk >> 1) * 32;
        const int r = tid >> 3, c4 = (tid & 7) * 4;
        f4 xq = *(const f4*)&x[(b0 + r) * NI + i0 + c4];
        #pragma unroll
        for (int jj = 0; jj < 4; ++jj) {
            smem[r * 33 + c4 + jj]        = xq[jj];
            smem[1056 + r * 33 + c4 + jj] = lt_of(xq[jj]);
        }
        __syncthreads();
        f4 xo, lo;
        #pragma unroll
        for (int jj = 0; jj < 4; ++jj) {
            xo[jj] = smem[(c4 + jj) * 33 + r];
            lo[jj] = smem[1056 + (c4 + jj) * 33 + r];
        }
        *(f4*)&xT [(i0 + r) * B + b0 + c4] = xo;
        *(f4*)&ltT[(i0 + r) * B + b0 + c4] = lo;
    }
    grid.sync();

    // ---- P1: layer-0 partials ----
    layer_partial(xT, ltT, fc0, v0, ph, ps, smem);
    grid.sync();

    // ---- P2: layer-0 finalize -> h0T, lt1T ----
    {
        int g = blk * 256 + tid;
        if (g < NO * B) {
            float sh = 0.f, ss = 0.f;
            #pragma unroll
            for (int s = 0; s < NSPLIT; ++s) {
                sh += ph[s * (NO * B) + g];
                ss += ps[s * (NO * B) + g];
            }
            float hv = fmaxf(sh * expf(ss), 0.0f);
            h0T[g]  = hv;
            lt1T[g] = lt_of(hv);
        }
    }
    grid.sync();

    // ---- P3: layer-1 partials (reuse ph/ps) ----
    layer_partial(h0T, lt1T, fc1, v1, ph, ps, smem);
    grid.sync();

    // ---- P4: layer-1 finalize -> h1T ----
    {
        int g = blk * 256 + tid;
        if (g < NO * B) {
            float sh = 0.f, ss = 0.f;
            #pragma unroll
            for (int s = 0; s < NSPLIT; ++s) {
                sh += ph[s * (NO * B) + g];
                ss += ps[s * (NO * B) + g];
            }
            h1T[g] = fmaxf(sh * expf(ss), 0.0f);
        }
    }
    grid.sync();

    // ---- P5: heads, y[b][c] = sum_o h0T[o][b]*hd0[c][o] + h1T[o][b]*hd1[c][o] ----
    if (blk < NC) {
        const int c = blk;
        const int w = tid >> 6, lane = tid & 63;
        const int ob = __builtin_amdgcn_readfirstlane(w * 256);
        float acc = 0.f;
        #pragma unroll
        for (int l = 0; l < 2; ++l) {
            const float* hd = l ? hd1 : hd0;
            const float* ht = l ? h1T : h0T;
            for (int oc = 0; oc < 256; oc += 8) {
                #pragma unroll
                for (int j = 0; j < 8; ++j) {
                    float wv = hd[c * NO + ob + oc + j];          // s_load (uniform)
                    acc = fmaf(wv, ht[(ob + oc + j) * B + lane], acc);
                }
            }
        }
        smem[w * B + lane] = acc;
        __syncthreads();
        if (tid < B) {
            float s = smem[tid] + smem[B + tid] + smem[2 * B + tid] + smem[3 * B + tid];
            y[tid * NC + c] = s;
        }
    }
}

extern "C" void kernel_launch(void* const* d_in, const int* in_sizes, int n_in,
                              void* d_out, int out_size, void* d_ws, size_t ws_size,
                              hipStream_t stream) {
    const float* x   = (const float*)d_in[0];
    const float* v0  = (const float*)d_in[1];
    const float* fc0 = (const float*)d_in[2];
    const float* hd0 = (const float*)d_in[3];
    const float* v1  = (const float*)d_in[4];
    const float* fc1 = (const float*)d_in[5];
    const float* hd1 = (const float*)d_in[6];
    float* y = (float*)d_out;

    float* ws   = (float*)d_ws;
    float* ph   = ws;                       // 8*65536 floats = 2 MB
    float* ps   = ph + NSPLIT * NO * B;     // 2 MB
    float* xT   = ps + NSPLIT * NO * B;     // 256 KB
    float* ltT  = xT + NI * B;
    float* h0T  = ltT + NI * B;
    float* lt1T = h0T + NO * B;
    float* h1T  = lt1T + NO * B;

    void* args[] = {(void*)&x, (void*)&v0, (void*)&fc0, (void*)&hd0,
                    (void*)&v1, (void*)&fc1, (void*)&hd1, (void*)&y,
                    (void*)&ph, (void*)&ps, (void*)&xT, (void*)&ltT,
                    (void*)&h0T, (void*)&lt1T, (void*)&h1T};
    hipLaunchCooperativeKernel((const void*)harsanyi_fused, dim3(GRID), dim3(256),
                               args, 0, stream);
}